// Round 1
// baseline (1036.201 us; speedup 1.0000x reference)
//
#include <hip/hip_runtime.h>
#include <cstddef>

// Problem constants
#define B_    16
#define SQ_   1024
#define SE_   1024
#define CIN_  256
#define CENC_ 256
#define DK_   64
#define DV_   64
#define H_    8
#define HD_   512          // H*DK == H*DV
#define NROWS 16384        // B * SQ  (== B * SE)
#define BN_EPS 1e-5f
#define NEG_SLOPE 0.01f

// ---------------------------------------------------------------------------
// Generic tiled GEMM: C[M,N] = A[M,K] @ W[N,K]^T      (A, W row-major)
// 64x64 tile per block, 256 threads, 4x4 micro-tile per thread, BK=16.
// M,N,K must be multiples of 64/64/16 (true for all uses here).
// ---------------------------------------------------------------------------
__global__ __launch_bounds__(256) void gemm64(const float* __restrict__ A,
                                              const float* __restrict__ W,
                                              float* __restrict__ C,
                                              int M, int N, int K) {
    __shared__ float As[64 * 16];
    __shared__ float Bs[16 * 68];   // padded stride 68 to soften bank conflicts

    const int tid = threadIdx.x;
    const int tx = tid & 15;        // 0..15 -> output cols tx*4..+3
    const int ty = tid >> 4;        // 0..15 -> output rows ty*4..+3
    const int m0 = blockIdx.y * 64;
    const int n0 = blockIdx.x * 64;

    const int lrow  = tid >> 2;     // 0..63
    const int lquad = tid & 3;      // 0..3 -> k sub-quad

    float acc[4][4] = {};

    for (int k0 = 0; k0 < K; k0 += 16) {
        float4 av = *(const float4*)(A + (size_t)(m0 + lrow) * K + k0 + lquad * 4);
        float4 wv = *(const float4*)(W + (size_t)(n0 + lrow) * K + k0 + lquad * 4);
        As[lrow * 16 + lquad * 4 + 0] = av.x;
        As[lrow * 16 + lquad * 4 + 1] = av.y;
        As[lrow * 16 + lquad * 4 + 2] = av.z;
        As[lrow * 16 + lquad * 4 + 3] = av.w;
        Bs[(lquad * 4 + 0) * 68 + lrow] = wv.x;
        Bs[(lquad * 4 + 1) * 68 + lrow] = wv.y;
        Bs[(lquad * 4 + 2) * 68 + lrow] = wv.z;
        Bs[(lquad * 4 + 3) * 68 + lrow] = wv.w;
        __syncthreads();

        #pragma unroll
        for (int k = 0; k < 16; ++k) {
            float a[4], b[4];
            #pragma unroll
            for (int i = 0; i < 4; ++i) a[i] = As[(ty * 4 + i) * 16 + k];
            #pragma unroll
            for (int j = 0; j < 4; ++j) b[j] = Bs[k * 68 + tx * 4 + j];
            #pragma unroll
            for (int i = 0; i < 4; ++i)
                #pragma unroll
                for (int j = 0; j < 4; ++j)
                    acc[i][j] += a[i] * b[j];
        }
        __syncthreads();
    }

    #pragma unroll
    for (int i = 0; i < 4; ++i)
        #pragma unroll
        for (int j = 0; j < 4; ++j)
            C[(size_t)(m0 + ty * 4 + i) * N + n0 + tx * 4 + j] = acc[i][j];
}

// ---------------------------------------------------------------------------
// Flash-style attention.  qh/kh/vh are [B*S, 512] with col = h*64 + d.
// One block = (64 q-rows, one head, one batch). 256 threads, 4x4 micro-tile.
// Online softmax; P reuses the K-tile LDS; no S matrix materialized.
// o written as [B*SQ, 512] with col = h*64 + e (head-major concat).
// ---------------------------------------------------------------------------
__global__ __launch_bounds__(256) void attn_kernel(const float* __restrict__ qh,
                                                   const float* __restrict__ kh,
                                                   const float* __restrict__ vh,
                                                   float* __restrict__ o) {
    __shared__ float Qs[64 * 65];
    __shared__ float KPs[64 * 65];  // K tile, then reused for P
    __shared__ float Vs[64 * 65];

    const int tid = threadIdx.x;
    const int tx = tid & 15;
    const int ty = tid >> 4;
    const int q0 = blockIdx.x * 64;
    const int h  = blockIdx.y;
    const int b  = blockIdx.z;
    const float scale = 0.125f;     // 1/sqrt(DK)

    // Load Q tile (pre-scaled)
    for (int idx = tid; idx < 4096; idx += 256) {
        int m = idx >> 6, d = idx & 63;
        Qs[m * 65 + d] = qh[(size_t)(b * SQ_ + q0 + m) * HD_ + h * DK_ + d] * scale;
    }

    float m_i[4], l_i[4], Oacc[4][4];
    #pragma unroll
    for (int i = 0; i < 4; ++i) { m_i[i] = -1e30f; l_i[i] = 0.f; }
    #pragma unroll
    for (int i = 0; i < 4; ++i)
        #pragma unroll
        for (int j = 0; j < 4; ++j) Oacc[i][j] = 0.f;

    for (int t0 = 0; t0 < SE_; t0 += 64) {
        __syncthreads();   // prior PV done (and Q load on first iter) before overwrite
        for (int idx = tid; idx < 4096; idx += 256) {
            int t = idx >> 6, d = idx & 63;
            size_t row = (size_t)(b * SE_ + t0 + t);
            KPs[t * 65 + d] = kh[row * HD_ + h * DK_ + d];
            Vs[t * 65 + d]  = vh[row * HD_ + h * DV_ + d];
        }
        __syncthreads();

        // S tile = Qs . Ks^T  (already scaled)
        float s[4][4];
        #pragma unroll
        for (int i = 0; i < 4; ++i)
            #pragma unroll
            for (int j = 0; j < 4; ++j) s[i][j] = 0.f;
        for (int k = 0; k < 64; ++k) {
            float a[4], bb[4];
            #pragma unroll
            for (int i = 0; i < 4; ++i) a[i] = Qs[(ty * 4 + i) * 65 + k];
            #pragma unroll
            for (int j = 0; j < 4; ++j) bb[j] = KPs[(tx * 4 + j) * 65 + k];
            #pragma unroll
            for (int i = 0; i < 4; ++i)
                #pragma unroll
                for (int j = 0; j < 4; ++j)
                    s[i][j] += a[i] * bb[j];
        }

        // Row-wise online softmax update. Row m = ty*4+i spans the 16 lanes
        // that share ty (tid bits 0..3 = tx) -> xor-butterfly width 16.
        float tm[4], mnew[4], alpha[4], rs[4];
        #pragma unroll
        for (int i = 0; i < 4; ++i) {
            tm[i] = fmaxf(fmaxf(s[i][0], s[i][1]), fmaxf(s[i][2], s[i][3]));
        }
        #pragma unroll
        for (int i = 0; i < 4; ++i) {
            tm[i] = fmaxf(tm[i], __shfl_xor(tm[i], 1));
            tm[i] = fmaxf(tm[i], __shfl_xor(tm[i], 2));
            tm[i] = fmaxf(tm[i], __shfl_xor(tm[i], 4));
            tm[i] = fmaxf(tm[i], __shfl_xor(tm[i], 8));
        }
        #pragma unroll
        for (int i = 0; i < 4; ++i) {
            mnew[i]  = fmaxf(m_i[i], tm[i]);
            alpha[i] = __expf(m_i[i] - mnew[i]);
            rs[i] = 0.f;
        }
        #pragma unroll
        for (int i = 0; i < 4; ++i)
            #pragma unroll
            for (int j = 0; j < 4; ++j) {
                s[i][j] = __expf(s[i][j] - mnew[i]);
                rs[i] += s[i][j];
            }
        #pragma unroll
        for (int i = 0; i < 4; ++i) {
            rs[i] += __shfl_xor(rs[i], 1);
            rs[i] += __shfl_xor(rs[i], 2);
            rs[i] += __shfl_xor(rs[i], 4);
            rs[i] += __shfl_xor(rs[i], 8);
            l_i[i] = l_i[i] * alpha[i] + rs[i];
            m_i[i] = mnew[i];
        }
        #pragma unroll
        for (int i = 0; i < 4; ++i)
            #pragma unroll
            for (int j = 0; j < 4; ++j) Oacc[i][j] *= alpha[i];

        __syncthreads();   // everyone done reading K before P overwrites it
        #pragma unroll
        for (int i = 0; i < 4; ++i)
            #pragma unroll
            for (int j = 0; j < 4; ++j)
                KPs[(ty * 4 + i) * 65 + tx * 4 + j] = s[i][j];
        __syncthreads();

        // Oacc += P . V
        for (int t = 0; t < 64; ++t) {
            float p_[4], v_[4];
            #pragma unroll
            for (int i = 0; i < 4; ++i) p_[i] = KPs[(ty * 4 + i) * 65 + t];
            #pragma unroll
            for (int j = 0; j < 4; ++j) v_[j] = Vs[t * 65 + tx * 4 + j];
            #pragma unroll
            for (int i = 0; i < 4; ++i)
                #pragma unroll
                for (int j = 0; j < 4; ++j)
                    Oacc[i][j] += p_[i] * v_[j];
        }
    }

    #pragma unroll
    for (int i = 0; i < 4; ++i) {
        float inv = 1.0f / l_i[i];
        #pragma unroll
        for (int j = 0; j < 4; ++j)
            o[(size_t)(b * SQ_ + q0 + ty * 4 + i) * HD_ + h * DV_ + tx * 4 + j] =
                Oacc[i][j] * inv;
    }
}

// ---------------------------------------------------------------------------
// BatchNorm statistics: per-channel sum / sumsq over all 16384 rows of p.
// One block = 64 rows; thread c owns channel c. fp32 atomics to global accums.
// ---------------------------------------------------------------------------
__global__ __launch_bounds__(256) void bn_stats(const float* __restrict__ p,
                                                float* __restrict__ gsum,
                                                float* __restrict__ gsumsq) {
    const int c  = threadIdx.x;
    const int r0 = blockIdx.x * 64;
    float s = 0.f, sq = 0.f;
    for (int r = 0; r < 64; ++r) {
        float v = p[(size_t)(r0 + r) * CIN_ + c];
        s  += v;
        sq += v * v;
    }
    atomicAdd(&gsum[c], s);
    atomicAdd(&gsumsq[c], sq);
}

__global__ void zero_stats(float* g) { g[threadIdx.x] = 0.f; }  // 512 threads

// ---------------------------------------------------------------------------
// Normalize + affine + LeakyReLU
// ---------------------------------------------------------------------------
__global__ __launch_bounds__(256) void bn_norm(const float* __restrict__ p,
                                               const float* __restrict__ gsum,
                                               const float* __restrict__ gsumsq,
                                               const float* __restrict__ gamma,
                                               const float* __restrict__ beta,
                                               float* __restrict__ out) {
    const int idx = blockIdx.x * 256 + threadIdx.x;
    const int c = idx & (CIN_ - 1);
    const float invN = 1.0f / (float)NROWS;
    float mean = gsum[c] * invN;
    float var  = gsumsq[c] * invN - mean * mean;
    float v = (p[idx] - mean) * rsqrtf(var + BN_EPS) * gamma[c] + beta[c];
    out[idx] = v >= 0.f ? v : NEG_SLOPE * v;
}

// ---------------------------------------------------------------------------
// kernel_launch
// ---------------------------------------------------------------------------
extern "C" void kernel_launch(void* const* d_in, const int* in_sizes, int n_in,
                              void* d_out, int out_size, void* d_ws, size_t ws_size,
                              hipStream_t stream) {
    const float* x     = (const float*)d_in[0];  // [16,1024,256]
    const float* q     = (const float*)d_in[1];  // [16,1024,256]
    const float* Wq    = (const float*)d_in[2];  // [8,64,256] -> flat [512,256]
    const float* Wk    = (const float*)d_in[3];
    const float* Wv    = (const float*)d_in[4];
    const float* Wp    = (const float*)d_in[5];  // [256,512]
    const float* gamma = (const float*)d_in[6];
    const float* beta  = (const float*)d_in[7];
    float* out = (float*)d_out;

    float* ws  = (float*)d_ws;
    // Workspace layout (floats):
    //   qh [16384,512] | kh [16384,512] | vh [16384,512] | o [16384,512]
    //   p [16384,256]  | stats [512]
    float* qh    = ws;
    float* kh    = qh + (size_t)NROWS * HD_;
    float* vh    = kh + (size_t)NROWS * HD_;
    float* o     = vh + (size_t)NROWS * HD_;
    float* p     = o  + (size_t)NROWS * HD_;
    float* stats = p  + (size_t)NROWS * CIN_;

    zero_stats<<<1, 512, 0, stream>>>(stats);

    // Projections: [16384,256] @ [512,256]^T -> [16384,512]
    gemm64<<<dim3(8, 256), 256, 0, stream>>>(q, Wq, qh, NROWS, HD_, CIN_);
    gemm64<<<dim3(8, 256), 256, 0, stream>>>(x, Wk, kh, NROWS, HD_, CENC_);
    gemm64<<<dim3(8, 256), 256, 0, stream>>>(x, Wv, vh, NROWS, HD_, CENC_);

    // Attention: grid (q-tiles, heads, batch)
    attn_kernel<<<dim3(SQ_ / 64, H_, B_), 256, 0, stream>>>(qh, kh, vh, o);

    // Output projection: [16384,512] @ [256,512]^T -> [16384,256]
    gemm64<<<dim3(4, 256), 256, 0, stream>>>(o, Wp, p, NROWS, CIN_, HD_);

    // BatchNorm stats + normalize + LeakyReLU
    bn_stats<<<256, 256, 0, stream>>>(p, stats, stats + 256);
    bn_norm<<<NROWS, 256, 0, stream>>>(p, stats, stats + 256, gamma, beta, out);
}

// Round 2
// 339.533 us; speedup vs baseline: 3.0518x; 3.0518x over previous
//
#include <hip/hip_runtime.h>
#include <cstddef>

// Problem constants
#define B_    16
#define SQ_   1024
#define SE_   1024
#define CIN_  256
#define CENC_ 256
#define DK_   64
#define DV_   64
#define H_    8
#define HD_   512          // H*DK == H*DV
#define NROWS 16384        // B * SQ  (== B * SE)
#define BN_EPS 1e-5f
#define NEG_SLOPE 0.01f

typedef __attribute__((ext_vector_type(8))) short bf16x8;   // 8 bf16 in 4 VGPRs
typedef __attribute__((ext_vector_type(4))) float f32x4;

__device__ __forceinline__ unsigned short f2bf(float f) {
    unsigned int u = __float_as_uint(f);
    unsigned int r = (u + 0x7FFFu + ((u >> 16) & 1u)) >> 16;   // RNE
    return (unsigned short)r;
}

// ---------------------------------------------------------------------------
// fp32 -> bf16 cast (with optional scale), vectorized by 4
// ---------------------------------------------------------------------------
__global__ __launch_bounds__(256) void cvt_bf16(const float* __restrict__ src,
                                                unsigned short* __restrict__ dst,
                                                int n4, float scale) {
    int i = blockIdx.x * 256 + threadIdx.x;
    if (i < n4) {
        float4 v = *(const float4*)(src + (size_t)i * 4);
        unsigned short o0 = f2bf(v.x * scale), o1 = f2bf(v.y * scale);
        unsigned short o2 = f2bf(v.z * scale), o3 = f2bf(v.w * scale);
        unsigned int lo = (unsigned int)o0 | ((unsigned int)o1 << 16);
        unsigned int hi = (unsigned int)o2 | ((unsigned int)o3 << 16);
        uint2 pk; pk.x = lo; pk.y = hi;
        *(uint2*)(dst + (size_t)i * 4) = pk;
    }
}

// ---------------------------------------------------------------------------
// MFMA GEMM: C[M,N] = A[M,K] @ W[N,K]^T   (bf16 inputs, fp32 accum)
// 64x64 tile / block, 256 threads = 4 waves, wave owns a 16x64 strip.
// BK=64 staged in LDS (stride 72 bf16 -> bank-balanced, 16B aligned rows).
// ---------------------------------------------------------------------------
template <bool OUT_BF16>
__global__ __launch_bounds__(256) void gemm_mfma(const unsigned short* __restrict__ A,
                                                 const unsigned short* __restrict__ W,
                                                 float* __restrict__ Cf,
                                                 unsigned short* __restrict__ Cb,
                                                 int M, int N, int K) {
    __shared__ __align__(16) unsigned short As[64 * 72];
    __shared__ __align__(16) unsigned short Ws[64 * 72];

    const int tid = threadIdx.x;
    const int w  = tid >> 6;       // wave 0..3
    const int l  = tid & 63;
    const int lq = l >> 4;         // quad 0..3
    const int lr = l & 15;
    const int m0 = blockIdx.y * 64;
    const int n0 = blockIdx.x * 64;

    const int sr = tid & 63;            // staging row
    const int sc = (tid >> 6) * 8;      // staging col chunk

    f32x4 acc[4] = {};

    for (int k0 = 0; k0 < K; k0 += 64) {
        __syncthreads();
        const unsigned short* Ar = A + (size_t)(m0 + sr) * K + k0;
        const unsigned short* Wr = W + (size_t)(n0 + sr) * K + k0;
        *(uint4*)&As[sr * 72 + sc]      = *(const uint4*)(Ar + sc);
        *(uint4*)&As[sr * 72 + sc + 32] = *(const uint4*)(Ar + sc + 32);
        *(uint4*)&Ws[sr * 72 + sc]      = *(const uint4*)(Wr + sc);
        *(uint4*)&Ws[sr * 72 + sc + 32] = *(const uint4*)(Wr + sc + 32);
        __syncthreads();

        #pragma unroll
        for (int ks = 0; ks < 2; ++ks) {
            bf16x8 a = *(bf16x8*)&As[(16 * w + lr) * 72 + ks * 32 + lq * 8];
            #pragma unroll
            for (int j = 0; j < 4; ++j) {
                bf16x8 bb = *(bf16x8*)&Ws[(16 * j + lr) * 72 + ks * 32 + lq * 8];
                acc[j] = __builtin_amdgcn_mfma_f32_16x16x32_bf16(a, bb, acc[j], 0, 0, 0);
            }
        }
    }

    // C/D layout: col = lane&15, row = quad*4 + reg
    #pragma unroll
    for (int j = 0; j < 4; ++j)
        #pragma unroll
        for (int r = 0; r < 4; ++r) {
            size_t row = (size_t)(m0 + 16 * w + lq * 4 + r);
            int col = n0 + 16 * j + lr;
            if (OUT_BF16) Cb[row * N + col] = f2bf(acc[j][r]);
            else          Cf[row * N + col] = acc[j][r];
        }
}

// ---------------------------------------------------------------------------
// MFMA flash attention. qh/kh/vh bf16 [B*S, 512], col = h*64 + d.
// Block = (64 q-rows, head, batch); wave owns 16 q-rows.
// Q scaled by 1/sqrt(dk) at weight-conversion time.
// ---------------------------------------------------------------------------
__global__ __launch_bounds__(256) void attn_mfma(const unsigned short* __restrict__ qh,
                                                 const unsigned short* __restrict__ kh,
                                                 const unsigned short* __restrict__ vh,
                                                 unsigned short* __restrict__ o) {
    __shared__ __align__(16) unsigned short Ks[64 * 72];   // [key][dk]
    __shared__ __align__(16) unsigned short Vt[64 * 72];   // [dv][key] (transposed)
    __shared__ __align__(16) unsigned short Ps[4][16 * 72];// per-wave P strip [m][key]

    const int tid = threadIdx.x;
    const int w  = tid >> 6;
    const int l  = tid & 63;
    const int lq = l >> 4;
    const int lr = l & 15;
    const int q0 = blockIdx.x * 64;
    const int h  = blockIdx.y;
    const int b  = blockIdx.z;

    // Q A-fragments, resident in registers: A[m=lr][k=lq*8+j (+32)]
    bf16x8 qf[2];
    {
        const unsigned short* qrow =
            qh + (size_t)(b * SQ_ + q0 + 16 * w + lr) * HD_ + h * DK_;
        qf[0] = *(const bf16x8*)(qrow + lq * 8);
        qf[1] = *(const bf16x8*)(qrow + 32 + lq * 8);
    }

    float m_i[4], l_i[4];
    f32x4 oacc[4] = {};
    #pragma unroll
    for (int r = 0; r < 4; ++r) { m_i[r] = -1e30f; l_i[r] = 0.f; }

    const int sr = tid & 63;
    const int sc = (tid >> 6) * 8;

    for (int t0 = 0; t0 < SE_; t0 += 64) {
        __syncthreads();
        {
            const unsigned short* krow = kh + (size_t)(b * SE_ + t0 + sr) * HD_ + h * DK_;
            *(uint4*)&Ks[sr * 72 + sc]      = *(const uint4*)(krow + sc);
            *(uint4*)&Ks[sr * 72 + sc + 32] = *(const uint4*)(krow + sc + 32);
            const unsigned short* vrow = vh + (size_t)(b * SE_ + t0 + sr) * HD_ + h * DV_;
            uint4 v0 = *(const uint4*)(vrow + sc);
            uint4 v1 = *(const uint4*)(vrow + sc + 32);
            const unsigned short* p0 = (const unsigned short*)&v0;
            const unsigned short* p1 = (const unsigned short*)&v1;
            #pragma unroll
            for (int jj = 0; jj < 8; ++jj) {
                Vt[(sc + jj) * 72 + sr]      = p0[jj];
                Vt[(sc + 32 + jj) * 72 + sr] = p1[jj];
            }
        }
        __syncthreads();

        // S strip: 4 n-tiles x 2 k-steps
        f32x4 s[4] = {};
        #pragma unroll
        for (int ks = 0; ks < 2; ++ks)
            #pragma unroll
            for (int j = 0; j < 4; ++j) {
                bf16x8 kf = *(bf16x8*)&Ks[(16 * j + lr) * 72 + ks * 32 + lq * 8];
                s[j] = __builtin_amdgcn_mfma_f32_16x16x32_bf16(qf[ks], kf, s[j], 0, 0, 0);
            }

        // Online softmax on C-layout rows (row = lq*4 + r, owned by 16 lanes of quad lq)
        float al[4], rs[4];
        #pragma unroll
        for (int r = 0; r < 4; ++r) {
            float mx = fmaxf(fmaxf(s[0][r], s[1][r]), fmaxf(s[2][r], s[3][r]));
            mx = fmaxf(mx, __shfl_xor(mx, 1));
            mx = fmaxf(mx, __shfl_xor(mx, 2));
            mx = fmaxf(mx, __shfl_xor(mx, 4));
            mx = fmaxf(mx, __shfl_xor(mx, 8));
            float mn = fmaxf(m_i[r], mx);
            al[r] = __expf(m_i[r] - mn);
            m_i[r] = mn;
            rs[r] = 0.f;
        }
        #pragma unroll
        for (int j = 0; j < 4; ++j)
            #pragma unroll
            for (int r = 0; r < 4; ++r) {
                float e = __expf(s[j][r] - m_i[r]);
                s[j][r] = e;
                rs[r] += e;
            }
        #pragma unroll
        for (int r = 0; r < 4; ++r) {
            rs[r] += __shfl_xor(rs[r], 1);
            rs[r] += __shfl_xor(rs[r], 2);
            rs[r] += __shfl_xor(rs[r], 4);
            rs[r] += __shfl_xor(rs[r], 8);
            l_i[r] = l_i[r] * al[r] + rs[r];
        }
        #pragma unroll
        for (int j = 0; j < 4; ++j)
            #pragma unroll
            for (int r = 0; r < 4; ++r) oacc[j][r] *= al[r];

        // P: C-layout -> wave-private LDS -> A-layout fragments
        unsigned short* Pw = Ps[w];
        #pragma unroll
        for (int j = 0; j < 4; ++j)
            #pragma unroll
            for (int r = 0; r < 4; ++r)
                Pw[(lq * 4 + r) * 72 + 16 * j + lr] = f2bf(s[j][r]);
        // cross-lane within the wave: drain LDS writes before reading back
        asm volatile("s_waitcnt lgkmcnt(0)" ::: "memory");

        #pragma unroll
        for (int ks = 0; ks < 2; ++ks) {
            bf16x8 pf = *(bf16x8*)&Pw[lr * 72 + ks * 32 + lq * 8];
            #pragma unroll
            for (int j = 0; j < 4; ++j) {
                bf16x8 vf = *(bf16x8*)&Vt[(16 * j + lr) * 72 + ks * 32 + lq * 8];
                oacc[j] = __builtin_amdgcn_mfma_f32_16x16x32_bf16(pf, vf, oacc[j], 0, 0, 0);
            }
        }
    }

    #pragma unroll
    for (int r = 0; r < 4; ++r) {
        float inv = 1.0f / l_i[r];
        #pragma unroll
        for (int j = 0; j < 4; ++j)
            o[(size_t)(b * SQ_ + q0 + 16 * w + lq * 4 + r) * HD_ + h * DV_ + 16 * j + lr] =
                f2bf(oacc[j][r] * inv);
    }
}

// ---------------------------------------------------------------------------
// BatchNorm stats + normalize (fp32, unchanged from R1)
// ---------------------------------------------------------------------------
__global__ __launch_bounds__(256) void bn_stats(const float* __restrict__ p,
                                                float* __restrict__ gsum,
                                                float* __restrict__ gsumsq) {
    const int c  = threadIdx.x;
    const int r0 = blockIdx.x * 64;
    float s = 0.f, sq = 0.f;
    for (int r = 0; r < 64; ++r) {
        float v = p[(size_t)(r0 + r) * CIN_ + c];
        s  += v;
        sq += v * v;
    }
    atomicAdd(&gsum[c], s);
    atomicAdd(&gsumsq[c], sq);
}

__global__ void zero_stats(float* g) { g[threadIdx.x] = 0.f; }  // 512 threads

__global__ __launch_bounds__(256) void bn_norm(const float* __restrict__ p,
                                               const float* __restrict__ gsum,
                                               const float* __restrict__ gsumsq,
                                               const float* __restrict__ gamma,
                                               const float* __restrict__ beta,
                                               float* __restrict__ out) {
    const int idx = blockIdx.x * 256 + threadIdx.x;
    const int c = idx & (CIN_ - 1);
    const float invN = 1.0f / (float)NROWS;
    float mean = gsum[c] * invN;
    float var  = gsumsq[c] * invN - mean * mean;
    float v = (p[idx] - mean) * rsqrtf(var + BN_EPS) * gamma[c] + beta[c];
    out[idx] = v >= 0.f ? v : NEG_SLOPE * v;
}

// ---------------------------------------------------------------------------
// kernel_launch
// ---------------------------------------------------------------------------
extern "C" void kernel_launch(void* const* d_in, const int* in_sizes, int n_in,
                              void* d_out, int out_size, void* d_ws, size_t ws_size,
                              hipStream_t stream) {
    const float* x     = (const float*)d_in[0];  // [16,1024,256]
    const float* q     = (const float*)d_in[1];  // [16,1024,256]
    const float* Wq    = (const float*)d_in[2];  // [8,64,256] -> [512,256]
    const float* Wk    = (const float*)d_in[3];
    const float* Wv    = (const float*)d_in[4];
    const float* Wp    = (const float*)d_in[5];  // [256,512]
    const float* gamma = (const float*)d_in[6];
    const float* beta  = (const float*)d_in[7];
    float* out = (float*)d_out;

    // Workspace layout (bytes, 256-aligned chunks)
    char* base = (char*)d_ws;
    unsigned short* qbf  = (unsigned short*)base;                    // 8.39 MB
    unsigned short* xbf  = (unsigned short*)(base + 8388608);        // 8.39 MB
    unsigned short* Wqb  = (unsigned short*)(base + 16777216);
    unsigned short* Wkb  = (unsigned short*)(base + 17039360);
    unsigned short* Wvb  = (unsigned short*)(base + 17301504);
    unsigned short* Wpb  = (unsigned short*)(base + 17563648);
    unsigned short* qh   = (unsigned short*)(base + 17825792);       // 16.78 MB
    unsigned short* kh   = (unsigned short*)(base + 34603008);
    unsigned short* vh   = (unsigned short*)(base + 51380224);
    unsigned short* o    = (unsigned short*)(base + 68157440);
    float*          p    = (float*)        (base + 84934656);        // 16.78 MB
    float*          stats= (float*)        (base + 101711872);       // 2 KB

    // Casts (scale 1/sqrt(DK)=0.125 folded into Wq)
    cvt_bf16<<<4096, 256, 0, stream>>>(q,  qbf, 1048576, 1.0f);
    cvt_bf16<<<4096, 256, 0, stream>>>(x,  xbf, 1048576, 1.0f);
    cvt_bf16<<<128,  256, 0, stream>>>(Wq, Wqb, 32768, 0.125f);
    cvt_bf16<<<128,  256, 0, stream>>>(Wk, Wkb, 32768, 1.0f);
    cvt_bf16<<<128,  256, 0, stream>>>(Wv, Wvb, 32768, 1.0f);
    cvt_bf16<<<128,  256, 0, stream>>>(Wp, Wpb, 32768, 1.0f);

    zero_stats<<<1, 512, 0, stream>>>(stats);

    // Projections: [16384,256] @ [512,256]^T -> bf16 [16384,512]
    gemm_mfma<true><<<dim3(8, 256), 256, 0, stream>>>(qbf, Wqb, nullptr, qh, NROWS, HD_, CIN_);
    gemm_mfma<true><<<dim3(8, 256), 256, 0, stream>>>(xbf, Wkb, nullptr, kh, NROWS, HD_, CENC_);
    gemm_mfma<true><<<dim3(8, 256), 256, 0, stream>>>(xbf, Wvb, nullptr, vh, NROWS, HD_, CENC_);

    // Attention
    attn_mfma<<<dim3(SQ_ / 64, H_, B_), 256, 0, stream>>>(qh, kh, vh, o);

    // Output projection: [16384,512] @ [256,512]^T -> fp32 [16384,256]
    gemm_mfma<false><<<dim3(4, 256), 256, 0, stream>>>(o, Wpb, p, nullptr, NROWS, CIN_, HD_);

    // BatchNorm + LeakyReLU
    bn_stats<<<256, 256, 0, stream>>>(p, stats, stats + 256);
    bn_norm<<<NROWS, 256, 0, stream>>>(p, stats, stats + 256, gamma, beta, out);
}

// Round 3
// 268.470 us; speedup vs baseline: 3.8597x; 1.2647x over previous
//
#include <hip/hip_runtime.h>
#include <cstddef>

#define B_    16
#define SQ_   1024
#define SE_   1024
#define CIN_  256
#define DK_   64
#define H_    8
#define HD_   512
#define NROWS 16384
#define BN_EPS 1e-5f
#define NEG_SLOPE 0.01f

typedef __attribute__((ext_vector_type(8))) short bf16x8;
typedef __attribute__((ext_vector_type(4))) float f32x4;

__device__ __forceinline__ unsigned short f2bf(float f) {  // RNE
    unsigned int u = __float_as_uint(f);
    return (unsigned short)((u + 0x7FFFu + ((u >> 16) & 1u)) >> 16);
}

// pack two f32 -> two bf16 (truncation) in one u32; lo -> low 16 bits
#if __has_builtin(__builtin_amdgcn_perm)
__device__ __forceinline__ unsigned int pack_trunc(float lo, float hi) {
    return __builtin_amdgcn_perm(__float_as_uint(hi), __float_as_uint(lo), 0x07060302u);
}
#else
__device__ __forceinline__ unsigned int pack_trunc(float lo, float hi) {
    return (__float_as_uint(lo) >> 16) | (__float_as_uint(hi) & 0xFFFF0000u);
}
#endif

#if __has_builtin(__builtin_amdgcn_exp2f)
#define EXP2F(x) __builtin_amdgcn_exp2f(x)
#else
#define EXP2F(x) exp2f(x)
#endif

// ---------------------------------------------------------------------------
// All four weight casts in one dispatch. Wq gets 0.125*log2(e) folded in
// (scale for 1/sqrt(dk) + exp2-domain softmax).
// ---------------------------------------------------------------------------
__global__ __launch_bounds__(256) void wcast(const float* __restrict__ Wq,
                                             const float* __restrict__ Wk,
                                             const float* __restrict__ Wv,
                                             const float* __restrict__ Wp,
                                             unsigned short* __restrict__ dWq,
                                             unsigned short* __restrict__ dWkv,
                                             unsigned short* __restrict__ dWp) {
    int i = blockIdx.x * 256 + threadIdx.x;    // float4 index, 4*32768 total
    int which = i >> 15, off = i & 32767;
    const float* s; unsigned short* d; float sc = 1.0f;
    if (which == 0)      { s = Wq; d = dWq; sc = 0.18033688011112042f; }
    else if (which == 1) { s = Wk; d = dWkv; }
    else if (which == 2) { s = Wv; d = dWkv + 131072; }
    else                 { s = Wp; d = dWp; }
    float4 v = *(const float4*)(s + (size_t)off * 4);
    ushort4 pk;
    pk.x = f2bf(v.x * sc); pk.y = f2bf(v.y * sc);
    pk.z = f2bf(v.z * sc); pk.w = f2bf(v.w * sc);
    *(ushort4*)(d + (size_t)off * 4) = pk;
}

// ---------------------------------------------------------------------------
// 128x128-tile MFMA GEMM: C[M,N] = A[M,K] @ W[N,K]^T
// 256 thr = 4 waves; wave owns 32 rows (2 m-frags x 8 j-tiles). BK=64.
// EPI 0: A f32 (fused bf16 cvt), out bf16 stride 512   (Q proj -> qh)
// EPI 1: A f32, cols<512 -> kh bf16; cols>=512 -> vT[b][h][e][t] packed
// EPI 2: A bf16, out f32 stride 256                    (out proj -> p)
// ---------------------------------------------------------------------------
template<int EPI>
__global__ __launch_bounds__(256) void gemm128(const void* __restrict__ Aptr,
                                               const unsigned short* __restrict__ W,
                                               void* __restrict__ out,
                                               unsigned short* __restrict__ out2,
                                               int K) {
    __shared__ __align__(16) unsigned short As[128 * 72];
    __shared__ __align__(16) unsigned short Ws[128 * 72];
    const int tid = threadIdx.x;
    const int w = tid >> 6, l = tid & 63, lq = l >> 4, lr = l & 15;
    const int n0 = blockIdx.x * 128, m0 = blockIdx.y * 128;
    const int srow = tid >> 1, shalf = (tid & 1) * 32;

    f32x4 acc[2][8] = {};

    for (int k0 = 0; k0 < K; k0 += 64) {
        __syncthreads();
        {
            const unsigned short* Wr = W + (size_t)(n0 + srow) * K + k0 + shalf;
            #pragma unroll
            for (int c = 0; c < 4; ++c)
                *(uint4*)&Ws[srow * 72 + shalf + c * 8] = *(const uint4*)(Wr + c * 8);
        }
        if (EPI < 2) {
            const float* Ar = (const float*)Aptr + (size_t)(m0 + srow) * K + k0 + shalf;
            #pragma unroll
            for (int c = 0; c < 4; ++c) {
                float4 u0 = *(const float4*)(Ar + c * 8);
                float4 u1 = *(const float4*)(Ar + c * 8 + 4);
                uint4 pk;
                pk.x = pack_trunc(u0.x, u0.y);
                pk.y = pack_trunc(u0.z, u0.w);
                pk.z = pack_trunc(u1.x, u1.y);
                pk.w = pack_trunc(u1.z, u1.w);
                *(uint4*)&As[srow * 72 + shalf + c * 8] = pk;
            }
        } else {
            const unsigned short* Ar = (const unsigned short*)Aptr + (size_t)(m0 + srow) * K + k0 + shalf;
            #pragma unroll
            for (int c = 0; c < 4; ++c)
                *(uint4*)&As[srow * 72 + shalf + c * 8] = *(const uint4*)(Ar + c * 8);
        }
        __syncthreads();

        #pragma unroll
        for (int ks = 0; ks < 2; ++ks) {
            bf16x8 a0 = *(bf16x8*)&As[(w * 32 + lr) * 72 + ks * 32 + lq * 8];
            bf16x8 a1 = *(bf16x8*)&As[(w * 32 + 16 + lr) * 72 + ks * 32 + lq * 8];
            #pragma unroll
            for (int j = 0; j < 8; ++j) {
                bf16x8 bb = *(bf16x8*)&Ws[(j * 16 + lr) * 72 + ks * 32 + lq * 8];
                acc[0][j] = __builtin_amdgcn_mfma_f32_16x16x32_bf16(a0, bb, acc[0][j], 0, 0, 0);
                acc[1][j] = __builtin_amdgcn_mfma_f32_16x16x32_bf16(a1, bb, acc[1][j], 0, 0, 0);
            }
        }
    }

    // Epilogue. C/D layout: col = lane&15, row = quad*4 + reg (verified R2).
    if (EPI == 0) {
        unsigned short* C = (unsigned short*)out;
        #pragma unroll
        for (int m = 0; m < 2; ++m)
            #pragma unroll
            for (int j = 0; j < 8; ++j)
                #pragma unroll
                for (int r = 0; r < 4; ++r)
                    C[(size_t)(m0 + w * 32 + m * 16 + lq * 4 + r) * 512 + n0 + j * 16 + lr] =
                        f2bf(acc[m][j][r]);
    } else if (EPI == 2) {
        float* C = (float*)out;
        #pragma unroll
        for (int m = 0; m < 2; ++m)
            #pragma unroll
            for (int j = 0; j < 8; ++j)
                #pragma unroll
                for (int r = 0; r < 4; ++r)
                    C[(size_t)(m0 + w * 32 + m * 16 + lq * 4 + r) * 256 + n0 + j * 16 + lr] =
                        acc[m][j][r];
    } else {
        if (n0 < 512) {   // K projection -> kh row-major
            unsigned short* C = (unsigned short*)out;
            #pragma unroll
            for (int m = 0; m < 2; ++m)
                #pragma unroll
                for (int j = 0; j < 8; ++j)
                    #pragma unroll
                    for (int r = 0; r < 4; ++r)
                        C[(size_t)(m0 + w * 32 + m * 16 + lq * 4 + r) * 512 + n0 + j * 16 + lr] =
                            f2bf(acc[m][j][r]);
        } else {          // V projection -> vT[b][h][e][t], 4 consecutive t packed
            #pragma unroll
            for (int m = 0; m < 2; ++m) {
                int row = m0 + w * 32 + m * 16 + lq * 4;   // r=0; all 4 r share b
                int bb = row >> 10, t = row & 1023;
                #pragma unroll
                for (int j = 0; j < 8; ++j) {
                    int colv = n0 - 512 + j * 16 + lr;
                    int hh = colv >> 6, e = colv & 63;
                    ushort4 pk;
                    pk.x = f2bf(acc[m][j][0]); pk.y = f2bf(acc[m][j][1]);
                    pk.z = f2bf(acc[m][j][2]); pk.w = f2bf(acc[m][j][3]);
                    *(ushort4*)&out2[(size_t)((bb * 8 + hh) * 64 + e) * 1024 + t] = pk;
                }
            }
        }
    }
}

// ---------------------------------------------------------------------------
// MFMA flash attention v2. qh/kh bf16 [B*S,512]; vT bf16 [B,H,64,SE].
// Block = 128 q-rows x (head,batch); wave owns 32 rows. No-max exp2 softmax
// (scale+log2e folded into Wq), lane-local l accumulation, trunc-bf16 P.
// ---------------------------------------------------------------------------
__global__ __launch_bounds__(256) void attn_mfma2(const unsigned short* __restrict__ qh,
                                                  const unsigned short* __restrict__ kh,
                                                  const unsigned short* __restrict__ vT,
                                                  unsigned short* __restrict__ o) {
    __shared__ __align__(16) unsigned short Ks[64 * 72];      // [key][d]
    __shared__ __align__(16) unsigned short Vs[64 * 72];      // [e][t]
    __shared__ __align__(16) unsigned short Ps[4][32 * 72];   // per-wave [m-row][key]

    const int tid = threadIdx.x;
    const int w = tid >> 6, l = tid & 63, lq = l >> 4, lr = l & 15;
    const int q0 = blockIdx.x * 128, h = blockIdx.y, b = blockIdx.z;

    bf16x8 qf[2][2];
    #pragma unroll
    for (int m = 0; m < 2; ++m) {
        const unsigned short* qr =
            qh + (size_t)(b * SQ_ + q0 + w * 32 + m * 16 + lr) * HD_ + h * DK_;
        qf[m][0] = *(const bf16x8*)(qr + lq * 8);
        qf[m][1] = *(const bf16x8*)(qr + 32 + lq * 8);
    }

    const unsigned short* kb = kh + (size_t)(b * SE_) * HD_ + h * DK_;
    const unsigned short* vb = vT + (size_t)((b * 8 + h) * 64) * 1024;

    const int se = tid >> 3;          // 0..31
    const int sc = (tid & 7) * 8;     // 8-elem chunk

    float l_i[2][4] = {};
    f32x4 oacc[2][4] = {};

    for (int t0 = 0; t0 < SE_; t0 += 64) {
        __syncthreads();
        #pragma unroll
        for (int ps = 0; ps < 2; ++ps) {
            int rr = se + ps * 32;
            *(uint4*)&Ks[rr * 72 + sc] = *(const uint4*)(kb + (size_t)(t0 + rr) * HD_ + sc);
            *(uint4*)&Vs[rr * 72 + sc] = *(const uint4*)(vb + (size_t)rr * 1024 + t0 + sc);
        }
        __syncthreads();

        f32x4 s[2][4] = {};
        #pragma unroll
        for (int ks = 0; ks < 2; ++ks)
            #pragma unroll
            for (int j = 0; j < 4; ++j) {
                bf16x8 kf = *(bf16x8*)&Ks[(j * 16 + lr) * 72 + ks * 32 + lq * 8];
                s[0][j] = __builtin_amdgcn_mfma_f32_16x16x32_bf16(qf[0][ks], kf, s[0][j], 0, 0, 0);
                s[1][j] = __builtin_amdgcn_mfma_f32_16x16x32_bf16(qf[1][ks], kf, s[1][j], 0, 0, 0);
            }

        // p = 2^s (natural-exp softmax, scale folded); lane-local l accum;
        // trunc-bf16 P into wave-private LDS strip in A-operand row layout.
        unsigned short* Pw = Ps[w];
        #pragma unroll
        for (int m = 0; m < 2; ++m)
            #pragma unroll
            for (int j = 0; j < 4; ++j)
                #pragma unroll
                for (int r = 0; r < 4; ++r) {
                    float e = EXP2F(s[m][j][r]);
                    l_i[m][r] += e;
                    Pw[(m * 16 + lq * 4 + r) * 72 + j * 16 + lr] =
                        (unsigned short)(__float_as_uint(e) >> 16);
                }
        asm volatile("s_waitcnt lgkmcnt(0)" ::: "memory");   // wave-local round trip

        #pragma unroll
        for (int ks = 0; ks < 2; ++ks) {
            bf16x8 pf0 = *(bf16x8*)&Pw[(lr) * 72 + ks * 32 + lq * 8];
            bf16x8 pf1 = *(bf16x8*)&Pw[(16 + lr) * 72 + ks * 32 + lq * 8];
            #pragma unroll
            for (int j = 0; j < 4; ++j) {
                bf16x8 vf = *(bf16x8*)&Vs[(j * 16 + lr) * 72 + ks * 32 + lq * 8];
                oacc[0][j] = __builtin_amdgcn_mfma_f32_16x16x32_bf16(pf0, vf, oacc[0][j], 0, 0, 0);
                oacc[1][j] = __builtin_amdgcn_mfma_f32_16x16x32_bf16(pf1, vf, oacc[1][j], 0, 0, 0);
            }
        }
    }

    #pragma unroll
    for (int m = 0; m < 2; ++m)
        #pragma unroll
        for (int r = 0; r < 4; ++r) {
            float t = l_i[m][r];
            t += __shfl_xor(t, 1); t += __shfl_xor(t, 2);
            t += __shfl_xor(t, 4); t += __shfl_xor(t, 8);
            float inv = 1.0f / t;
            #pragma unroll
            for (int j = 0; j < 4; ++j)
                o[(size_t)(b * SQ_ + q0 + w * 32 + m * 16 + lq * 4 + r) * HD_ + h * DK_ +
                  j * 16 + lr] = f2bf(oacc[m][j][r] * inv);
        }
}

// ---------------------------------------------------------------------------
// BatchNorm stats + normalize + LeakyReLU
// ---------------------------------------------------------------------------
__global__ __launch_bounds__(256) void bn_stats(const float* __restrict__ p,
                                                float* __restrict__ gsum,
                                                float* __restrict__ gsumsq) {
    const int c  = threadIdx.x;
    const int r0 = blockIdx.x * 64;
    float s = 0.f, sq = 0.f;
    for (int r = 0; r < 64; ++r) {
        float v = p[(size_t)(r0 + r) * CIN_ + c];
        s  += v;
        sq += v * v;
    }
    atomicAdd(&gsum[c], s);
    atomicAdd(&gsumsq[c], sq);
}

__global__ void zero_stats(float* g) { g[threadIdx.x] = 0.f; }  // 512 threads

__global__ __launch_bounds__(256) void bn_norm4(const float* __restrict__ p,
                                                const float* __restrict__ gsum,
                                                const float* __restrict__ gsumsq,
                                                const float* __restrict__ gamma,
                                                const float* __restrict__ beta,
                                                float* __restrict__ out) {
    int i = blockIdx.x * 256 + threadIdx.x;     // float4 index
    int c0 = (i * 4) & 255;
    const float invN = 1.0f / (float)NROWS;
    float4 pv = *(const float4*)(p + (size_t)i * 4);
    float vals[4] = {pv.x, pv.y, pv.z, pv.w};
    float res[4];
    #pragma unroll
    for (int k = 0; k < 4; ++k) {
        int c = c0 + k;
        float mean = gsum[c] * invN;
        float var  = gsumsq[c] * invN - mean * mean;
        float v = (vals[k] - mean) * rsqrtf(var + BN_EPS) * gamma[c] + beta[c];
        res[k] = v >= 0.f ? v : NEG_SLOPE * v;
    }
    float4 ov = {res[0], res[1], res[2], res[3]};
    *(float4*)(out + (size_t)i * 4) = ov;
}

// ---------------------------------------------------------------------------
// kernel_launch
// ---------------------------------------------------------------------------
extern "C" void kernel_launch(void* const* d_in, const int* in_sizes, int n_in,
                              void* d_out, int out_size, void* d_ws, size_t ws_size,
                              hipStream_t stream) {
    const float* x     = (const float*)d_in[0];
    const float* q     = (const float*)d_in[1];
    const float* Wq    = (const float*)d_in[2];
    const float* Wk    = (const float*)d_in[3];
    const float* Wv    = (const float*)d_in[4];
    const float* Wp    = (const float*)d_in[5];
    const float* gamma = (const float*)d_in[6];
    const float* beta  = (const float*)d_in[7];
    float* out = (float*)d_out;

    char* base = (char*)d_ws;
    unsigned short* Wqb  = (unsigned short*)(base + 0);          //  512x256 bf16
    unsigned short* Wkvb = (unsigned short*)(base + 262144);     // 1024x256 bf16 (Wk|Wv)
    unsigned short* Wpb  = (unsigned short*)(base + 786432);     //  256x512 bf16
    unsigned short* qh   = (unsigned short*)(base + 1048576);    // 16384x512 bf16
    unsigned short* khb  = (unsigned short*)(base + 17825792);   // 16384x512 bf16
    unsigned short* vTb  = (unsigned short*)(base + 34603008);   // [16,8,64,1024] bf16
    unsigned short* ob   = (unsigned short*)(base + 51380224);   // 16384x512 bf16
    float*          pbuf = (float*)        (base + 68157440);    // 16384x256 f32
    float*          stats= (float*)        (base + 84934656);    // 512 f32

    wcast<<<512, 256, 0, stream>>>(Wq, Wk, Wv, Wp, Wqb, Wkvb, Wpb);
    zero_stats<<<1, 512, 0, stream>>>(stats);

    // Q projection (scale+log2e folded into Wqb)
    gemm128<0><<<dim3(4, 128), 256, 0, stream>>>(q, Wqb, qh, nullptr, 256);
    // K+V projections fused; V written transposed
    gemm128<1><<<dim3(8, 128), 256, 0, stream>>>(x, Wkvb, khb, vTb, 256);

    attn_mfma2<<<dim3(8, 8, 16), 256, 0, stream>>>(qh, khb, vTb, ob);

    // Output projection -> f32 p
    gemm128<2><<<dim3(2, 128), 256, 0, stream>>>(ob, Wpb, pbuf, nullptr, 512);

    bn_stats<<<256, 256, 0, stream>>>(pbuf, stats, stats + 256);
    bn_norm4<<<4096, 256, 0, stream>>>(pbuf, stats, stats + 256, gamma, beta, out);
}